// Round 3
// baseline (231.555 us; speedup 1.0000x reference)
//
#include <hip/hip_runtime.h>
#include <hip/hip_bf16.h>

// ---------------------------------------------------------------------------
// GraphSage forward on MI355X — round 3.
//   cvt W1,W2,W3 -> bf16; cvt emb -> bf16 (embB, 51.2MB, L3-resident)
//   build_A0 (bf16 gather) ; comb[:, :256] = relu(A0 @ W1^T)
//   zero comb32 (fp32 [4096,256])
//   fused_h1 (M-tile=32, LDS 32KB, 5 blocks/CU): gather [32x512] bf16 A-tile
//     into swizzled LDS, GEMM vs W1^T (N=256), relu, in-LDS batch-segment
//     column sums, atomicAdd into comb32  (h1 buffer eliminated)
//   pack_comb: comb[:,256:512] = bf16(comb32/25)
//   embd = relu(comb @ W2^T); out = embd @ W3^T (fp32)
// ---------------------------------------------------------------------------

typedef __bf16  bf16x8 __attribute__((ext_vector_type(8)));
typedef __bf16  bf16x4 __attribute__((ext_vector_type(4)));
typedef float   f32x4  __attribute__((ext_vector_type(4)));

#define FEAT      256
#define BATCH     4096
#define F1        25
#define F2        10
#define NROWS1    (BATCH * F1)        // 102400
#define EMB_ELEMS (100000 * 256)      // 25,600,000

__device__ __forceinline__ uint2 pack4_bf16(float a, float b, float c, float d) {
    union { __bf16 h[4]; uint2 u; } p;
    p.h[0] = (__bf16)a; p.h[1] = (__bf16)b; p.h[2] = (__bf16)c; p.h[3] = (__bf16)d;
    return p.u;
}

// LDS swizzle for [R][512] bf16 tile (1024 B/row): byte ^= (row&7)<<4.
__device__ __forceinline__ int swz(int row, int colbyte) {
    return row * 1024 + (colbyte ^ ((row & 7) << 4));
}

// ---- fp32 -> bf16 (8 elems/thread) ----------------------------------------
__global__ __launch_bounds__(256) void cvt_bf16_8(const float* __restrict__ in,
                                                  __bf16* __restrict__ out, int n8) {
    int i = blockIdx.x * 256 + threadIdx.x;
    if (i < n8) {
        float4 v0 = reinterpret_cast<const float4*>(in)[i * 2];
        float4 v1 = reinterpret_cast<const float4*>(in)[i * 2 + 1];
        uint4 o;
        uint2 a = pack4_bf16(v0.x, v0.y, v0.z, v0.w);
        uint2 b = pack4_bf16(v1.x, v1.y, v1.z, v1.w);
        o.x = a.x; o.y = a.y; o.z = b.x; o.w = b.y;
        reinterpret_cast<uint4*>(out)[i] = o;
    }
}

// ---- zero fp32 buffer -----------------------------------------------------
__global__ __launch_bounds__(256) void zero_f32(float* __restrict__ p, int n4) {
    int i = blockIdx.x * 256 + threadIdx.x;
    if (i < n4) reinterpret_cast<float4*>(p)[i] = float4{0.f, 0.f, 0.f, 0.f};
}

// ---- build A0: [B, 512]  left=embB[T0], right=mean25(embB[T1]) ------------
__global__ __launch_bounds__(256) void build_A0(const int* __restrict__ T0,
                                                const int* __restrict__ T1,
                                                const __bf16* __restrict__ embB,
                                                __bf16* __restrict__ A0) {
    int b    = blockIdx.x * 4 + (threadIdx.x >> 6);
    int lane = threadIdx.x & 63;           // bf16x4 index (64*4 = 256 cols)
    int t0 = T0[b];
    bf16x4 L = *reinterpret_cast<const bf16x4*>(embB + (size_t)t0 * 256 + lane * 4);
    float s0 = 0.f, s1 = 0.f, s2 = 0.f, s3 = 0.f;
    for (int f = 0; f < F1; ++f) {
        int t1 = T1[b * F1 + f];
        bf16x4 v = *reinterpret_cast<const bf16x4*>(embB + (size_t)t1 * 256 + lane * 4);
        s0 += (float)v[0]; s1 += (float)v[1]; s2 += (float)v[2]; s3 += (float)v[3];
    }
    const float r = 1.0f / (float)F1;
    __bf16* row = A0 + (size_t)b * 512;
    *reinterpret_cast<bf16x4*>(row + lane * 4) = L;
    reinterpret_cast<uint2*>(row + 256)[lane] = pack4_bf16(s0 * r, s1 * r, s2 * r, s3 * r);
}

// ---- fused hop-1/2: gather + GEMM + relu + batch-segment reduce -----------
// grid.x = NROWS1/32 = 3200; 256 threads (4 waves); block tile 32(M) x 256(N).
// LDS: 32KB A-tile, reused as 32x256 fp32 result tile for the reduction.
__global__ __launch_bounds__(256) void fused_h1(const int* __restrict__ T1,
                                                const int* __restrict__ T2,
                                                const __bf16* __restrict__ embB,
                                                const __bf16* __restrict__ W1b,
                                                float* __restrict__ comb32) {
    __shared__ __align__(16) char At[32 * 1024];   // 32 rows x 512 bf16, swizzled
    float* Lf = reinterpret_cast<float*>(At);      // reused: 32 x 256 fp32
    const int tid = threadIdx.x;
    const int m0  = blockIdx.x * 32;

    // ---- gather phase: 16 lanes per row, 16 rows in parallel, 2 iters ----
    {
        const int lane16 = tid & 15;
        const int rgrp   = tid >> 4;
        const int cb     = lane16 * 32;            // byte col within 512B half
#pragma unroll
        for (int it = 0; it < 2; ++it) {
            const int rl   = it * 16 + rgrp;
            const int grow = m0 + rl;
            const int t1   = T1[grow];
            int idx[F2];
#pragma unroll
            for (int j = 0; j < F2; ++j) idx[j] = T2[(size_t)grow * F2 + j];
            const __bf16* src = embB + (size_t)t1 * 256 + lane16 * 16;
            bf16x8 L0 = *reinterpret_cast<const bf16x8*>(src);
            bf16x8 L1 = *reinterpret_cast<const bf16x8*>(src + 8);
            *reinterpret_cast<bf16x8*>(At + swz(rl, cb))      = L0;
            *reinterpret_cast<bf16x8*>(At + swz(rl, cb + 16)) = L1;
            float acc[16];
#pragma unroll
            for (int e = 0; e < 16; ++e) acc[e] = 0.f;
#pragma unroll
            for (int j = 0; j < F2; ++j) {
                const __bf16* s2 = embB + (size_t)idx[j] * 256 + lane16 * 16;
                bf16x8 v0 = *reinterpret_cast<const bf16x8*>(s2);
                bf16x8 v1 = *reinterpret_cast<const bf16x8*>(s2 + 8);
#pragma unroll
                for (int e = 0; e < 8; ++e) { acc[e] += (float)v0[e]; acc[8 + e] += (float)v1[e]; }
            }
            bf16x8 R0, R1;
#pragma unroll
            for (int e = 0; e < 8; ++e) {
                R0[e] = (__bf16)(acc[e] * 0.1f);
                R1[e] = (__bf16)(acc[8 + e] * 0.1f);
            }
            *reinterpret_cast<bf16x8*>(At + swz(rl, 512 + cb))      = R0;
            *reinterpret_cast<bf16x8*>(At + swz(rl, 512 + cb + 16)) = R1;
        }
    }
    __syncthreads();

    // ---- GEMM phase: wave wid covers cols n0..n0+63, rows m0..m0+31 ------
    const int wid  = tid >> 6;
    const int lane = tid & 63;
    const int n0   = wid * 64;
    const int lr   = lane & 15;
    const int kg   = lane >> 4;

    f32x4 acc[2][4] = {};
    const __bf16* Wbase = W1b + (size_t)(n0 + lr) * 512 + kg * 8;

    for (int kt = 0; kt < 512; kt += 32) {
        bf16x8 a[2], b[4];
#pragma unroll
        for (int i = 0; i < 2; ++i)
            a[i] = *reinterpret_cast<const bf16x8*>(At + swz(lr + i * 16, kt * 2 + kg * 16));
#pragma unroll
        for (int i = 0; i < 4; ++i)
            b[i] = *reinterpret_cast<const bf16x8*>(Wbase + (size_t)i * 16 * 512 + kt);
#pragma unroll
        for (int mi = 0; mi < 2; ++mi)
#pragma unroll
            for (int ni = 0; ni < 4; ++ni)
                acc[mi][ni] = __builtin_amdgcn_mfma_f32_16x16x32_bf16(a[mi], b[ni], acc[mi][ni], 0, 0, 0);
    }

    // ---- relu + stage fp32 tile in LDS (reuse At) ------------------------
    __syncthreads();   // all waves done reading At
    const int orow = (lane >> 4) * 4;
    const int ocol = lane & 15;
#pragma unroll
    for (int mi = 0; mi < 2; ++mi)
#pragma unroll
        for (int ni = 0; ni < 4; ++ni)
#pragma unroll
            for (int j = 0; j < 4; ++j)
                Lf[(mi * 16 + orow + j) * 256 + (n0 + ni * 16 + ocol)] =
                    fmaxf(acc[mi][ni][j], 0.0f);
    __syncthreads();

    // ---- per-batch column sums -> atomic accumulate into comb32 ----------
    {
        const int col    = tid;                     // 256 cols
        const int bfirst = m0 / F1;
        const int blast  = (m0 + 31) / F1;
        for (int b = bfirst; b <= blast; ++b) {
            int r0 = b * F1;     if (r0 < m0)      r0 = m0;
            int r1 = b * F1 + F1; if (r1 > m0 + 32) r1 = m0 + 32;
            float s = 0.f;
            for (int r = r0; r < r1; ++r) s += Lf[(r - m0) * 256 + col];
            atomicAdd(&comb32[(size_t)b * 256 + col], s);
        }
    }
}

// ---- pack: comb[b, 256:512] = bf16(comb32[b]/25) --------------------------
__global__ __launch_bounds__(256) void pack_comb(const float* __restrict__ comb32,
                                                 __bf16* __restrict__ comb) {
    int b    = blockIdx.x * 4 + (threadIdx.x >> 6);
    int lane = threadIdx.x & 63;
    float4 v = reinterpret_cast<const float4*>(comb32 + (size_t)b * 256)[lane];
    const float r = 1.0f / (float)F1;
    reinterpret_cast<uint2*>(comb + (size_t)b * 512 + 256)[lane] =
        pack4_bf16(v.x * r, v.y * r, v.z * r, v.w * r);
}

// ---- GEMM: C = relu(A @ W^T), A[M,K] bf16, W[N,K] bf16, C bf16 (ldc) ------
__global__ __launch_bounds__(256) void gemm_relu_bf16(const __bf16* __restrict__ A,
                                                      const __bf16* __restrict__ W,
                                                      __bf16* __restrict__ C,
                                                      int K, int ldc) {
    int wid  = threadIdx.x >> 6;
    int lane = threadIdx.x & 63;
    int m0 = blockIdx.x * 128 + (wid >> 1) * 64;
    int n0 = blockIdx.y * 128 + (wid & 1) * 64;
    int lr = lane & 15;
    int kg = lane >> 4;

    f32x4 acc[4][4] = {};
    const __bf16* Abase = A + (size_t)(m0 + lr) * K + kg * 8;
    const __bf16* Wbase = W + (size_t)(n0 + lr) * K + kg * 8;

    for (int kt = 0; kt < K; kt += 32) {
        bf16x8 a[4], b[4];
#pragma unroll
        for (int i = 0; i < 4; ++i)
            a[i] = *reinterpret_cast<const bf16x8*>(Abase + (size_t)i * 16 * K + kt);
#pragma unroll
        for (int i = 0; i < 4; ++i)
            b[i] = *reinterpret_cast<const bf16x8*>(Wbase + (size_t)i * 16 * K + kt);
#pragma unroll
        for (int mi = 0; mi < 4; ++mi)
#pragma unroll
            for (int ni = 0; ni < 4; ++ni)
                acc[mi][ni] = __builtin_amdgcn_mfma_f32_16x16x32_bf16(a[mi], b[ni], acc[mi][ni], 0, 0, 0);
    }

    int orow = (lane >> 4) * 4;
    int ocol = lane & 15;
#pragma unroll
    for (int mi = 0; mi < 4; ++mi)
#pragma unroll
        for (int ni = 0; ni < 4; ++ni)
#pragma unroll
            for (int j = 0; j < 4; ++j) {
                float v = fmaxf(acc[mi][ni][j], 0.0f);
                C[(size_t)(m0 + mi * 16 + orow + j) * ldc + (n0 + ni * 16 + ocol)] = (__bf16)v;
            }
}

// ---- final GEMM: out = embd @ W3^T, M=4096, N=64, K=256, fp32 out ---------
__global__ __launch_bounds__(256) void gemm_out(const __bf16* __restrict__ A,
                                                const __bf16* __restrict__ W,
                                                float* __restrict__ C) {
    const int K = 256;
    int wid  = threadIdx.x >> 6;
    int lane = threadIdx.x & 63;
    int m0 = blockIdx.x * 128 + wid * 32;
    int lr = lane & 15;
    int kg = lane >> 4;

    f32x4 acc[2][4] = {};
    const __bf16* Abase = A + (size_t)(m0 + lr) * K + kg * 8;
    const __bf16* Wbase = W + (size_t)lr * K + kg * 8;

    for (int kt = 0; kt < K; kt += 32) {
        bf16x8 a[2], b[4];
#pragma unroll
        for (int i = 0; i < 2; ++i)
            a[i] = *reinterpret_cast<const bf16x8*>(Abase + (size_t)i * 16 * K + kt);
#pragma unroll
        for (int i = 0; i < 4; ++i)
            b[i] = *reinterpret_cast<const bf16x8*>(Wbase + (size_t)i * 16 * K + kt);
#pragma unroll
        for (int mi = 0; mi < 2; ++mi)
#pragma unroll
            for (int ni = 0; ni < 4; ++ni)
                acc[mi][ni] = __builtin_amdgcn_mfma_f32_16x16x32_bf16(a[mi], b[ni], acc[mi][ni], 0, 0, 0);
    }

    int orow = (lane >> 4) * 4;
    int ocol = lane & 15;
#pragma unroll
    for (int mi = 0; mi < 2; ++mi)
#pragma unroll
        for (int ni = 0; ni < 4; ++ni)
#pragma unroll
            for (int j = 0; j < 4; ++j)
                C[(size_t)(m0 + mi * 16 + orow + j) * 64 + (ni * 16 + ocol)] = acc[mi][ni][j];
}

extern "C" void kernel_launch(void* const* d_in, const int* in_sizes, int n_in,
                              void* d_out, int out_size, void* d_ws, size_t ws_size,
                              hipStream_t stream) {
    const int*   T0  = (const int*)d_in[0];
    const int*   T1  = (const int*)d_in[1];
    const int*   T2  = (const int*)d_in[2];
    const float* emb = (const float*)d_in[3];
    const float* W1  = (const float*)d_in[4];
    const float* W2  = (const float*)d_in[5];
    const float* W3  = (const float*)d_in[6];
    float* out = (float*)d_out;

    char* ws = (char*)d_ws;
    __bf16* W1b    = (__bf16*)(ws);                  //   262144
    __bf16* W2b    = (__bf16*)(ws + 262144);         //   262144
    __bf16* W3b    = (__bf16*)(ws + 524288);         //    32768
    __bf16* A0     = (__bf16*)(ws + 557056);         //  4194304
    __bf16* embd   = (__bf16*)(ws + 4751360);        //  2097152
    __bf16* comb   = (__bf16*)(ws + 6848512);        //  4194304
    float*  comb32 = (float*)(ws + 11042816);        //  4194304
    __bf16* embB   = (__bf16*)(ws + 15237120);       // 51200000 -> ends 66437120

    // weights + emb -> bf16
    cvt_bf16_8<<<dim3(131072 / 8 / 256), dim3(256), 0, stream>>>(W1, W1b, 131072 / 8);
    cvt_bf16_8<<<dim3(131072 / 8 / 256), dim3(256), 0, stream>>>(W2, W2b, 131072 / 8);
    cvt_bf16_8<<<dim3(16384 / 8 / 256), dim3(256), 0, stream>>>(W3, W3b, 16384 / 8);
    cvt_bf16_8<<<dim3(EMB_ELEMS / 8 / 256), dim3(256), 0, stream>>>(emb, embB, EMB_ELEMS / 8);

    // hop-0 branch
    build_A0<<<dim3(BATCH / 4), dim3(256), 0, stream>>>(T0, T1, embB, A0);
    gemm_relu_bf16<<<dim3(BATCH / 128, 2), dim3(256), 0, stream>>>(A0, W1b, comb, 512, 512);

    // hop-1/2 branch: zero accumulator, fused gather+GEMM+reduce, pack mean
    zero_f32<<<dim3(BATCH * 256 / 4 / 256), dim3(256), 0, stream>>>(comb32, BATCH * 256 / 4);
    fused_h1<<<dim3(NROWS1 / 32), dim3(256), 0, stream>>>(T1, T2, embB, W1b, comb32);
    pack_comb<<<dim3(BATCH / 4), dim3(256), 0, stream>>>(comb32, comb);

    // layer 2 + classifier
    gemm_relu_bf16<<<dim3(BATCH / 128, 2), dim3(256), 0, stream>>>(comb, W2b, embd, 512, 256);
    gemm_out<<<dim3(BATCH / 128), dim3(256), 0, stream>>>(embd, W3b, out);
}

// Round 4
// 173.301 us; speedup vs baseline: 1.3361x; 1.3361x over previous
//
#include <hip/hip_runtime.h>
#include <hip/hip_bf16.h>

// ---------------------------------------------------------------------------
// GraphSage forward on MI355X — round 4: linearity restructure.
//   Wzy[512,256] = bf16([W1L ; W1R])   (W1[n,0:256] rows 0..255; W1[n,256:512] rows 256..511)
//   ZY[100000,512] = emb @ Wzy^T  (row t = [Z[t] | Y[t]]), fp32 A cvt in staging
//   h0[b]     = relu(Z[T0[b]] + (1/25) sum_f Y[T1[b,f]])          -> comb[:, :256]
//   h1mean[b] = (1/25) sum_f relu(Z[T1[b,f]] + (1/10) sum_j Y[T2]) -> comb[:, 256:]
//   embd = relu(comb @ W2^T); out = embd @ W3^T
// No W-streaming per gather row, no h1 buffer, no atomics.
// ---------------------------------------------------------------------------

typedef __bf16  bf16x8 __attribute__((ext_vector_type(8)));
typedef float   f32x4  __attribute__((ext_vector_type(4)));

#define BATCH     4096
#define F1        25
#define F2        10
#define NNODES    100000
#define ZY_NT     3125          // 100000 / 32 M-tiles (exact)
#define ZY_BLOCKS 256

__device__ __forceinline__ uint2 pack4_bf16(float a, float b, float c, float d) {
    union { __bf16 h[4]; uint2 u; } p;
    p.h[0] = (__bf16)a; p.h[1] = (__bf16)b; p.h[2] = (__bf16)c; p.h[3] = (__bf16)d;
    return p.u;
}

// ---- fp32 -> bf16 (8 elems/thread), for W2/W3 -----------------------------
__global__ __launch_bounds__(256) void cvt_bf16_8(const float* __restrict__ in,
                                                  __bf16* __restrict__ out, int n8) {
    int i = blockIdx.x * 256 + threadIdx.x;
    if (i < n8) {
        float4 v0 = reinterpret_cast<const float4*>(in)[i * 2];
        float4 v1 = reinterpret_cast<const float4*>(in)[i * 2 + 1];
        uint4 o;
        uint2 a = pack4_bf16(v0.x, v0.y, v0.z, v0.w);
        uint2 b = pack4_bf16(v1.x, v1.y, v1.z, v1.w);
        o.x = a.x; o.y = a.y; o.z = b.x; o.w = b.y;
        reinterpret_cast<uint4*>(out)[i] = o;
    }
}

// ---- build Wzy[512][256] bf16 from W1 fp32 [256][512] ---------------------
__global__ __launch_bounds__(256) void prep_wzy(const float* __restrict__ W1,
                                                __bf16* __restrict__ Wzy) {
    int i = blockIdx.x * 256 + threadIdx.x;    // 16384 threads, bf16x8 each
    int r  = i >> 5;                           // output row 0..511
    int c0 = (i & 31) * 8;
    const float* src = (r < 256) ? (W1 + (size_t)r * 512 + c0)
                                 : (W1 + (size_t)(r - 256) * 512 + 256 + c0);
    float4 a = reinterpret_cast<const float4*>(src)[0];
    float4 b = reinterpret_cast<const float4*>(src)[1];
    uint4 o;
    uint2 pa = pack4_bf16(a.x, a.y, a.z, a.w);
    uint2 pb = pack4_bf16(b.x, b.y, b.z, b.w);
    o.x = pa.x; o.y = pa.y; o.z = pb.x; o.w = pb.y;
    *reinterpret_cast<uint4*>(Wzy + (size_t)r * 256 + c0) = o;
}

// ---- ZY = emb @ Wzy^T : M=100000, N=512, K=256 ----------------------------
// 256 persistent blocks x 512 threads (8 waves, 1 block/CU). Each wave holds
// its 64-col W slice in registers (32 x bf16x8 = 128 VGPR). A staged fp32->
// bf16 into 16KB LDS tiles (M-tile 32), double-buffered, swizzled.
__global__ __launch_bounds__(512, 2) void gemm_ZY(const float* __restrict__ emb,
                                                  const __bf16* __restrict__ Wzy,
                                                  __bf16* __restrict__ ZY) {
    __shared__ __align__(16) char Abuf[2][16384];   // [32 rows][512B], XOR-swizzled
    const int tid  = threadIdx.x;
    const int wid  = tid >> 6;
    const int lane = tid & 63;
    const int lr   = lane & 15;
    const int kg   = lane >> 4;
    const int n0   = wid * 64;

    // preload W frags for this wave's n-slice
    bf16x8 wfrag[4][8];
    {
        const __bf16* Wb = Wzy + (size_t)(n0 + lr) * 256 + kg * 8;
#pragma unroll
        for (int ni = 0; ni < 4; ++ni)
#pragma unroll
            for (int kt = 0; kt < 8; ++kt)
                wfrag[ni][kt] = *reinterpret_cast<const bf16x8*>(Wb + ni * 16 * 256 + kt * 32);
    }

    // staging geometry: thread covers bf16 bytes [tid*32, +32) of the tile
    const int o0   = tid * 32;
    const int rs   = o0 >> 9;                      // LDS row 0..31
    const int x0   = o0 & 511;
    const int sw0  = rs * 512 + ((x0)      ^ ((rs & 7) << 4));
    const int sw1  = rs * 512 + ((x0 + 16) ^ ((rs & 7) << 4));

    int t = blockIdx.x;
    float4 ld0[4];
    {
        const float4* src = reinterpret_cast<const float4*>(emb + (size_t)t * 8192 + tid * 16);
#pragma unroll
        for (int q = 0; q < 4; ++q) ld0[q] = src[q];
    }
    int cur = 0;

    for (; t < ZY_NT; t += ZY_BLOCKS) {
        // stage current tile into Abuf[cur] (fp32 -> bf16)
        {
            bf16x8 c0v, c1v;
#pragma unroll
            for (int e = 0; e < 4; ++e) {
                c0v[e]     = (__bf16)ld0[0][e];
                c0v[4 + e] = (__bf16)ld0[1][e];
                c1v[e]     = (__bf16)ld0[2][e];
                c1v[4 + e] = (__bf16)ld0[3][e];
            }
            *reinterpret_cast<bf16x8*>(Abuf[cur] + sw0) = c0v;
            *reinterpret_cast<bf16x8*>(Abuf[cur] + sw1) = c1v;
        }
        // issue next tile's loads (in flight during compute)
        int tn = t + ZY_BLOCKS;
        float4 ld1[4] = {};
        if (tn < ZY_NT) {
            const float4* src = reinterpret_cast<const float4*>(emb + (size_t)tn * 8192 + tid * 16);
#pragma unroll
            for (int q = 0; q < 4; ++q) ld1[q] = src[q];
        }
        __syncthreads();

        // compute 32x512 tile: wave does 32M x 64N
        f32x4 acc[2][4] = {};
        const char* Ab = Abuf[cur];
#pragma unroll
        for (int kt = 0; kt < 8; ++kt) {
            bf16x8 a[2];
#pragma unroll
            for (int mi = 0; mi < 2; ++mi) {
                int r  = mi * 16 + lr;
                int by = kt * 64 + kg * 16;
                a[mi] = *reinterpret_cast<const bf16x8*>(Ab + r * 512 + (by ^ ((r & 7) << 4)));
            }
#pragma unroll
            for (int mi = 0; mi < 2; ++mi)
#pragma unroll
                for (int ni = 0; ni < 4; ++ni)
                    acc[mi][ni] = __builtin_amdgcn_mfma_f32_16x16x32_bf16(a[mi], wfrag[ni][kt], acc[mi][ni], 0, 0, 0);
        }

        // store (D layout: row=(lane>>4)*4+j, col=lane&15)
        const int orow = (lane >> 4) * 4;
        const int ocol = lane & 15;
        const int m0   = t * 32;
#pragma unroll
        for (int mi = 0; mi < 2; ++mi)
#pragma unroll
            for (int ni = 0; ni < 4; ++ni)
#pragma unroll
                for (int j = 0; j < 4; ++j)
                    ZY[(size_t)(m0 + mi * 16 + orow + j) * 512 + (n0 + ni * 16 + ocol)] =
                        (__bf16)acc[mi][ni][j];

#pragma unroll
        for (int q = 0; q < 4; ++q) ld0[q] = ld1[q];
        cur ^= 1;
    }
}

// ---- h0: comb[b, 0:256] = relu(Z[T0[b]] + mean_f Y[T1[b,f]]) --------------
// 1 wave per batch; halves split the f-list; combine via shfl_xor(32).
__global__ __launch_bounds__(256) void h0_kernel(const int* __restrict__ T0,
                                                 const int* __restrict__ T1,
                                                 const __bf16* __restrict__ ZY,
                                                 __bf16* __restrict__ comb) {
    int b    = blockIdx.x * 4 + (threadIdx.x >> 6);
    int lane = threadIdx.x & 63;
    int h    = lane >> 5;
    int c    = lane & 31;                       // 16B chunk: cols [c*8, c*8+8)
    float s[8] = {};
    for (int f = h; f < F1; f += 2) {
        int t = T1[b * F1 + f];
        bf16x8 v = *reinterpret_cast<const bf16x8*>(ZY + (size_t)t * 512 + 256 + c * 8);
#pragma unroll
        for (int e = 0; e < 8; ++e) s[e] += (float)v[e];
    }
    float p[8];
    if (h) {
        int t0 = T0[b];
        bf16x8 z = *reinterpret_cast<const bf16x8*>(ZY + (size_t)t0 * 512 + c * 8);
#pragma unroll
        for (int e = 0; e < 8; ++e) p[e] = s[e] * (1.0f / F1) + (float)z[e];
    } else {
#pragma unroll
        for (int e = 0; e < 8; ++e) p[e] = s[e] * (1.0f / F1);
    }
    bf16x8 outv;
#pragma unroll
    for (int e = 0; e < 8; ++e) {
        float tot = p[e] + __shfl_xor(p[e], 32);
        outv[e] = (__bf16)fmaxf(tot, 0.0f);
    }
    if (h == 0)
        *reinterpret_cast<bf16x8*>(comb + (size_t)b * 512 + c * 8) = outv;
}

// ---- h1: comb[b, 256:512] = (1/25) sum_f relu(Z[T1]+(1/10) sum_j Y[T2]) ---
// 1 block per batch (4 waves); wave handles f = wv, wv+4, ...; halves split j.
__global__ __launch_bounds__(256) void h1_kernel(const int* __restrict__ T1,
                                                 const int* __restrict__ T2,
                                                 const __bf16* __restrict__ ZY,
                                                 __bf16* __restrict__ comb) {
    __shared__ float red[4][256];
    const int b    = blockIdx.x;
    const int wv   = threadIdx.x >> 6;
    const int lane = threadIdx.x & 63;
    const int h    = lane >> 5;
    const int c    = lane & 31;
    float macc[8] = {};
    for (int f = wv; f < F1; f += 4) {
        const int r  = b * F1 + f;
        const int t1 = T1[r];
        float s[8] = {};
        for (int j = h; j < F2; j += 2) {
            int t2 = T2[(size_t)r * F2 + j];
            bf16x8 v = *reinterpret_cast<const bf16x8*>(ZY + (size_t)t2 * 512 + 256 + c * 8);
#pragma unroll
            for (int e = 0; e < 8; ++e) s[e] += (float)v[e];
        }
        float p[8];
        if (h) {
            bf16x8 z = *reinterpret_cast<const bf16x8*>(ZY + (size_t)t1 * 512 + c * 8);
#pragma unroll
            for (int e = 0; e < 8; ++e) p[e] = s[e] * (1.0f / F2) + (float)z[e];
        } else {
#pragma unroll
            for (int e = 0; e < 8; ++e) p[e] = s[e] * (1.0f / F2);
        }
#pragma unroll
        for (int e = 0; e < 8; ++e) {
            float tot = p[e] + __shfl_xor(p[e], 32);
            macc[e] += fmaxf(tot, 0.0f);
        }
    }
    if (h == 0) {
#pragma unroll
        for (int e = 0; e < 8; ++e) red[wv][c * 8 + e] = macc[e];
    }
    __syncthreads();
    int col = threadIdx.x;
    float sum = red[0][col] + red[1][col] + red[2][col] + red[3][col];
    comb[(size_t)b * 512 + 256 + col] = (__bf16)(sum * (1.0f / F1));
}

// ---- GEMM: C = relu(A @ W^T), A[M,K] bf16, W[N,K] bf16, C bf16 (ldc) ------
__global__ __launch_bounds__(256) void gemm_relu_bf16(const __bf16* __restrict__ A,
                                                      const __bf16* __restrict__ W,
                                                      __bf16* __restrict__ C,
                                                      int K, int ldc) {
    int wid  = threadIdx.x >> 6;
    int lane = threadIdx.x & 63;
    int m0 = blockIdx.x * 128 + (wid >> 1) * 64;
    int n0 = blockIdx.y * 128 + (wid & 1) * 64;
    int lr = lane & 15;
    int kg = lane >> 4;

    f32x4 acc[4][4] = {};
    const __bf16* Abase = A + (size_t)(m0 + lr) * K + kg * 8;
    const __bf16* Wbase = W + (size_t)(n0 + lr) * K + kg * 8;

    for (int kt = 0; kt < K; kt += 32) {
        bf16x8 a[4], b[4];
#pragma unroll
        for (int i = 0; i < 4; ++i)
            a[i] = *reinterpret_cast<const bf16x8*>(Abase + (size_t)i * 16 * K + kt);
#pragma unroll
        for (int i = 0; i < 4; ++i)
            b[i] = *reinterpret_cast<const bf16x8*>(Wbase + (size_t)i * 16 * K + kt);
#pragma unroll
        for (int mi = 0; mi < 4; ++mi)
#pragma unroll
            for (int ni = 0; ni < 4; ++ni)
                acc[mi][ni] = __builtin_amdgcn_mfma_f32_16x16x32_bf16(a[mi], b[ni], acc[mi][ni], 0, 0, 0);
    }

    int orow = (lane >> 4) * 4;
    int ocol = lane & 15;
#pragma unroll
    for (int mi = 0; mi < 4; ++mi)
#pragma unroll
        for (int ni = 0; ni < 4; ++ni)
#pragma unroll
            for (int j = 0; j < 4; ++j) {
                float v = fmaxf(acc[mi][ni][j], 0.0f);
                C[(size_t)(m0 + mi * 16 + orow + j) * ldc + (n0 + ni * 16 + ocol)] = (__bf16)v;
            }
}

// ---- final GEMM: out = embd @ W3^T, M=4096, N=64, K=256, fp32 out ---------
__global__ __launch_bounds__(256) void gemm_out(const __bf16* __restrict__ A,
                                                const __bf16* __restrict__ W,
                                                float* __restrict__ C) {
    const int K = 256;
    int wid  = threadIdx.x >> 6;
    int lane = threadIdx.x & 63;
    int m0 = blockIdx.x * 128 + wid * 32;
    int lr = lane & 15;
    int kg = lane >> 4;

    f32x4 acc[2][4] = {};
    const __bf16* Abase = A + (size_t)(m0 + lr) * K + kg * 8;
    const __bf16* Wbase = W + (size_t)lr * K + kg * 8;

    for (int kt = 0; kt < K; kt += 32) {
        bf16x8 a[2], b[4];
#pragma unroll
        for (int i = 0; i < 2; ++i)
            a[i] = *reinterpret_cast<const bf16x8*>(Abase + (size_t)i * 16 * K + kt);
#pragma unroll
        for (int i = 0; i < 4; ++i)
            b[i] = *reinterpret_cast<const bf16x8*>(Wbase + (size_t)i * 16 * K + kt);
#pragma unroll
        for (int mi = 0; mi < 2; ++mi)
#pragma unroll
            for (int ni = 0; ni < 4; ++ni)
                acc[mi][ni] = __builtin_amdgcn_mfma_f32_16x16x32_bf16(a[mi], b[ni], acc[mi][ni], 0, 0, 0);
    }

    int orow = (lane >> 4) * 4;
    int ocol = lane & 15;
#pragma unroll
    for (int mi = 0; mi < 2; ++mi)
#pragma unroll
        for (int ni = 0; ni < 4; ++ni)
#pragma unroll
            for (int j = 0; j < 4; ++j)
                C[(size_t)(m0 + mi * 16 + orow + j) * 64 + (ni * 16 + ocol)] = acc[mi][ni][j];
}

extern "C" void kernel_launch(void* const* d_in, const int* in_sizes, int n_in,
                              void* d_out, int out_size, void* d_ws, size_t ws_size,
                              hipStream_t stream) {
    const int*   T0  = (const int*)d_in[0];
    const int*   T1  = (const int*)d_in[1];
    const int*   T2  = (const int*)d_in[2];
    const float* emb = (const float*)d_in[3];
    const float* W1  = (const float*)d_in[4];
    const float* W2  = (const float*)d_in[5];
    const float* W3  = (const float*)d_in[6];
    float* out = (float*)d_out;

    char* ws = (char*)d_ws;
    __bf16* Wzy  = (__bf16*)(ws);                  //   262144
    __bf16* W2b  = (__bf16*)(ws + 262144);         //   262144
    __bf16* W3b  = (__bf16*)(ws + 524288);         //    32768
    __bf16* comb = (__bf16*)(ws + 557056);         //  4194304
    __bf16* embd = (__bf16*)(ws + 4751360);        //  2097152
    __bf16* ZY   = (__bf16*)(ws + 6848512);        // 102400000 -> ends 109248512

    // weights
    prep_wzy<<<dim3(64), dim3(256), 0, stream>>>(W1, Wzy);
    cvt_bf16_8<<<dim3(64), dim3(256), 0, stream>>>(W2, W2b, 131072 / 8);
    cvt_bf16_8<<<dim3(8), dim3(256), 0, stream>>>(W3, W3b, 16384 / 8);

    // per-node linear halves: ZY[t] = [Z[t] | Y[t]]
    gemm_ZY<<<dim3(ZY_BLOCKS), dim3(512), 0, stream>>>(emb, Wzy, ZY);

    // gather stages
    h0_kernel<<<dim3(BATCH / 4), dim3(256), 0, stream>>>(T0, T1, ZY, comb);
    h1_kernel<<<dim3(BATCH), dim3(256), 0, stream>>>(T1, T2, ZY, comb);

    // layer 2 + classifier
    gemm_relu_bf16<<<dim3(BATCH / 128, 2), dim3(256), 0, stream>>>(comb, W2b, embd, 512, 256);
    gemm_out<<<dim3(BATCH / 128), dim3(256), 0, stream>>>(embd, W3b, out);
}

// Round 5
// 134.654 us; speedup vs baseline: 1.7196x; 1.2870x over previous
//
#include <hip/hip_runtime.h>
#include <hip/hip_bf16.h>

// ---------------------------------------------------------------------------
// GraphSage forward on MI355X — round 5: fp8 gather table.
//   Wzy[512,256] = bf16([W1L ; W1R])
//   gemm_ZY: Ztab[100000,256] bf16 = emb@W1L^T ; Y8[100000,256] fp8 = emb@W1R^T
//   agg_kernel (1 block/batch):
//     comb[b, :256]  = relu(Ztab[T0] + (1/25) sum_f Y8[T1[b,f]])
//     comb[b, 256:]  = (1/25) sum_f relu(Ztab[T1[b,f]] + (1/10) sum_j Y8[T2])
//   embd = relu(comb @ W2^T); out = embd @ W3^T
// ---------------------------------------------------------------------------

typedef __bf16  bf16x8 __attribute__((ext_vector_type(8)));
typedef __bf16  bf16x4 __attribute__((ext_vector_type(4)));
typedef float   f32x4  __attribute__((ext_vector_type(4)));
typedef float   f32x2  __attribute__((ext_vector_type(2)));

#define BATCH     4096
#define F1        25
#define F2        10
#define NNODES    100000
#define ZY_NT     3125          // 100000 / 32 M-tiles
#define ZY_BLOCKS 512

__device__ __forceinline__ uint2 pack4_bf16(float a, float b, float c, float d) {
    union { __bf16 h[4]; uint2 u; } p;
    p.h[0] = (__bf16)a; p.h[1] = (__bf16)b; p.h[2] = (__bf16)c; p.h[3] = (__bf16)d;
    return p.u;
}

// ---- fp32 -> bf16 (8 elems/thread), for W2/W3 -----------------------------
__global__ __launch_bounds__(256) void cvt_bf16_8(const float* __restrict__ in,
                                                  __bf16* __restrict__ out, int n8) {
    int i = blockIdx.x * 256 + threadIdx.x;
    if (i < n8) {
        float4 v0 = reinterpret_cast<const float4*>(in)[i * 2];
        float4 v1 = reinterpret_cast<const float4*>(in)[i * 2 + 1];
        uint4 o;
        uint2 a = pack4_bf16(v0.x, v0.y, v0.z, v0.w);
        uint2 b = pack4_bf16(v1.x, v1.y, v1.z, v1.w);
        o.x = a.x; o.y = a.y; o.z = b.x; o.w = b.y;
        reinterpret_cast<uint4*>(out)[i] = o;
    }
}

// ---- build Wzy[512][256] bf16 from W1 fp32 [256][512] ---------------------
__global__ __launch_bounds__(256) void prep_wzy(const float* __restrict__ W1,
                                                __bf16* __restrict__ Wzy) {
    int i = blockIdx.x * 256 + threadIdx.x;
    int r  = i >> 5;
    int c0 = (i & 31) * 8;
    const float* src = (r < 256) ? (W1 + (size_t)r * 512 + c0)
                                 : (W1 + (size_t)(r - 256) * 512 + 256 + c0);
    float4 a = reinterpret_cast<const float4*>(src)[0];
    float4 b = reinterpret_cast<const float4*>(src)[1];
    uint4 o;
    uint2 pa = pack4_bf16(a.x, a.y, a.z, a.w);
    uint2 pb = pack4_bf16(b.x, b.y, b.z, b.w);
    o.x = pa.x; o.y = pa.y; o.z = pb.x; o.w = pb.y;
    *reinterpret_cast<uint4*>(Wzy + (size_t)r * 256 + c0) = o;
}

// ---- Ztab/Y8 producer GEMM: M=100000, N=512, K=256 ------------------------
// 512 blocks x 512 threads (8 waves). Wave n-slice: wid 0..3 -> Z cols,
// wid 4..7 -> Y cols (fp8 out). W slice in registers; A staged fp32->bf16
// into double-buffered swizzled LDS; epilogue repacks via per-wave LDS tile.
__global__ __launch_bounds__(512, 2) void gemm_ZY(const float* __restrict__ emb,
                                                  const __bf16* __restrict__ Wzy,
                                                  __bf16* __restrict__ Ztab,
                                                  unsigned char* __restrict__ Y8) {
    __shared__ __align__(16) char Abuf[2][16384];        // [32 rows][512B], swizzled
    __shared__ __align__(16) __bf16 Ybuf[8][32][72];     // epilogue repack tiles
    const int tid  = threadIdx.x;
    const int wid  = tid >> 6;
    const int lane = tid & 63;
    const int lr   = lane & 15;
    const int kg   = lane >> 4;
    const int n0   = wid * 64;

    bf16x8 wfrag[4][8];
    {
        const __bf16* Wb = Wzy + (size_t)(n0 + lr) * 256 + kg * 8;
#pragma unroll
        for (int ni = 0; ni < 4; ++ni)
#pragma unroll
            for (int kt = 0; kt < 8; ++kt)
                wfrag[ni][kt] = *reinterpret_cast<const bf16x8*>(Wb + ni * 16 * 256 + kt * 32);
    }

    const int o0   = tid * 32;
    const int rs   = o0 >> 9;
    const int x0   = o0 & 511;
    const int sw0  = rs * 512 + ((x0)      ^ ((rs & 7) << 4));
    const int sw1  = rs * 512 + ((x0 + 16) ^ ((rs & 7) << 4));

    int t = blockIdx.x;
    float4 ld0[4];
    {
        const float4* src = reinterpret_cast<const float4*>(emb + (size_t)t * 8192 + tid * 16);
#pragma unroll
        for (int q = 0; q < 4; ++q) ld0[q] = src[q];
    }
    int cur = 0;

    for (; t < ZY_NT; t += ZY_BLOCKS) {
        {
            bf16x8 c0v, c1v;
#pragma unroll
            for (int e = 0; e < 4; ++e) {
                c0v[e]     = (__bf16)ld0[0][e];
                c0v[4 + e] = (__bf16)ld0[1][e];
                c1v[e]     = (__bf16)ld0[2][e];
                c1v[4 + e] = (__bf16)ld0[3][e];
            }
            *reinterpret_cast<bf16x8*>(Abuf[cur] + sw0) = c0v;
            *reinterpret_cast<bf16x8*>(Abuf[cur] + sw1) = c1v;
        }
        int tn = t + ZY_BLOCKS;
        float4 ld1[4] = {};
        if (tn < ZY_NT) {
            const float4* src = reinterpret_cast<const float4*>(emb + (size_t)tn * 8192 + tid * 16);
#pragma unroll
            for (int q = 0; q < 4; ++q) ld1[q] = src[q];
        }
        __syncthreads();

        f32x4 acc[2][4] = {};
        const char* Ab = Abuf[cur];
#pragma unroll
        for (int kt = 0; kt < 8; ++kt) {
            bf16x8 a[2];
#pragma unroll
            for (int mi = 0; mi < 2; ++mi) {
                int r  = mi * 16 + lr;
                int by = kt * 64 + kg * 16;
                a[mi] = *reinterpret_cast<const bf16x8*>(Ab + r * 512 + (by ^ ((r & 7) << 4)));
            }
#pragma unroll
            for (int mi = 0; mi < 2; ++mi)
#pragma unroll
                for (int ni = 0; ni < 4; ++ni)
                    acc[mi][ni] = __builtin_amdgcn_mfma_f32_16x16x32_bf16(a[mi], wfrag[ni][kt], acc[mi][ni], 0, 0, 0);
        }

        // ---- epilogue: stage wave tile (32x64) in LDS, write coalesced ---
        const int orow = (lane >> 4) * 4;
        const int ocol = lane & 15;
        const int m0   = t * 32;
#pragma unroll
        for (int mi = 0; mi < 2; ++mi)
#pragma unroll
            for (int ni = 0; ni < 4; ++ni)
#pragma unroll
                for (int j = 0; j < 4; ++j)
                    Ybuf[wid][mi * 16 + orow + j][ni * 16 + ocol] = (__bf16)acc[mi][ni][j];
        // wave-private slice: in-order LDS, no barrier needed
        const int row = lane & 31;
        const int cg  = (lane >> 5) * 32;
        if (wid < 4) {
#pragma unroll
            for (int q = 0; q < 4; ++q) {
                bf16x8 v = *reinterpret_cast<bf16x8*>(&Ybuf[wid][row][cg + q * 8]);
                *reinterpret_cast<bf16x8*>(Ztab + (size_t)(m0 + row) * 256 + n0 + cg + q * 8) = v;
            }
        } else {
#pragma unroll
            for (int q = 0; q < 4; ++q) {
                bf16x8 v = *reinterpret_cast<bf16x8*>(&Ybuf[wid][row][cg + q * 8]);
                int w0 = 0, w1 = 0;
                w0 = __builtin_amdgcn_cvt_pk_fp8_f32((float)v[0], (float)v[1], w0, false);
                w0 = __builtin_amdgcn_cvt_pk_fp8_f32((float)v[2], (float)v[3], w0, true);
                w1 = __builtin_amdgcn_cvt_pk_fp8_f32((float)v[4], (float)v[5], w1, false);
                w1 = __builtin_amdgcn_cvt_pk_fp8_f32((float)v[6], (float)v[7], w1, true);
                uint2 o; o.x = (unsigned)w0; o.y = (unsigned)w1;
                *reinterpret_cast<uint2*>(Y8 + (size_t)(m0 + row) * 256 + (n0 - 256) + cg + q * 8) = o;
            }
        }

#pragma unroll
        for (int q = 0; q < 4; ++q) ld0[q] = ld1[q];
        cur ^= 1;
    }
}

// ---- merged aggregation: h0 + h1 ------------------------------------------
// 1 block (4 waves) per batch. Lane l owns cols [l*4, l*4+4) — fully local.
__global__ __launch_bounds__(256) void agg_kernel(const int* __restrict__ T0,
                                                  const int* __restrict__ T1,
                                                  const int* __restrict__ T2,
                                                  const __bf16* __restrict__ Ztab,
                                                  const unsigned char* __restrict__ Y8,
                                                  __bf16* __restrict__ comb) {
    __shared__ float red1[4][256];
    __shared__ float red0[4][256];
    const int b    = blockIdx.x;
    const int wv   = threadIdx.x >> 6;
    const int lane = threadIdx.x & 63;
    float macc[4] = {};
    float h0y[4]  = {};

    for (int f = wv; f < F1; f += 4) {
        const int r  = __builtin_amdgcn_readfirstlane(b * F1 + f);
        const int t1 = T1[r];
        int idx[F2];
#pragma unroll
        for (int j = 0; j < F2; ++j) idx[j] = T2[(size_t)r * F2 + j];

        bf16x4 z = *reinterpret_cast<const bf16x4*>(Ztab + (size_t)t1 * 256 + lane * 4);
        unsigned int y1 = *reinterpret_cast<const unsigned int*>(Y8 + (size_t)t1 * 256 + lane * 4);
        float sy[4] = {};
#pragma unroll
        for (int j = 0; j < F2; ++j) {
            unsigned int yv = *reinterpret_cast<const unsigned int*>(Y8 + (size_t)idx[j] * 256 + lane * 4);
            f32x2 lo = __builtin_amdgcn_cvt_pk_f32_fp8(yv, false);
            f32x2 hi = __builtin_amdgcn_cvt_pk_f32_fp8(yv, true);
            sy[0] += lo[0]; sy[1] += lo[1]; sy[2] += hi[0]; sy[3] += hi[1];
        }
        {
            f32x2 lo = __builtin_amdgcn_cvt_pk_f32_fp8(y1, false);
            f32x2 hi = __builtin_amdgcn_cvt_pk_f32_fp8(y1, true);
            h0y[0] += lo[0]; h0y[1] += lo[1]; h0y[2] += hi[0]; h0y[3] += hi[1];
        }
#pragma unroll
        for (int e = 0; e < 4; ++e)
            macc[e] += fmaxf((float)z[e] + sy[e] * (1.0f / F2), 0.0f);
    }

    float4 t1v; t1v.x = macc[0]; t1v.y = macc[1]; t1v.z = macc[2]; t1v.w = macc[3];
    float4 t0v; t0v.x = h0y[0];  t0v.y = h0y[1];  t0v.z = h0y[2];  t0v.w = h0y[3];
    *reinterpret_cast<float4*>(&red1[wv][lane * 4]) = t1v;
    *reinterpret_cast<float4*>(&red0[wv][lane * 4]) = t0v;
    __syncthreads();

    const int col = threadIdx.x;
    float s1 = red1[0][col] + red1[1][col] + red1[2][col] + red1[3][col];
    float s0 = red0[0][col] + red0[1][col] + red0[2][col] + red0[3][col];
    const int t0 = T0[b];
    float z0 = (float)Ztab[(size_t)t0 * 256 + col];
    comb[(size_t)b * 512 + col]       = (__bf16)fmaxf(z0 + s0 * (1.0f / F1), 0.0f);
    comb[(size_t)b * 512 + 256 + col] = (__bf16)(s1 * (1.0f / F1));
}

// ---- GEMM: C = relu(A @ W^T), A[M,K] bf16, W[N,K] bf16, C bf16 (ldc) ------
__global__ __launch_bounds__(256) void gemm_relu_bf16(const __bf16* __restrict__ A,
                                                      const __bf16* __restrict__ W,
                                                      __bf16* __restrict__ C,
                                                      int K, int ldc) {
    int wid  = threadIdx.x >> 6;
    int lane = threadIdx.x & 63;
    int m0 = blockIdx.x * 128 + (wid >> 1) * 64;
    int n0 = blockIdx.y * 128 + (wid & 1) * 64;
    int lr = lane & 15;
    int kg = lane >> 4;

    f32x4 acc[4][4] = {};
    const __bf16* Abase = A + (size_t)(m0 + lr) * K + kg * 8;
    const __bf16* Wbase = W + (size_t)(n0 + lr) * K + kg * 8;

    for (int kt = 0; kt < K; kt += 32) {
        bf16x8 a[4], b[4];
#pragma unroll
        for (int i = 0; i < 4; ++i)
            a[i] = *reinterpret_cast<const bf16x8*>(Abase + (size_t)i * 16 * K + kt);
#pragma unroll
        for (int i = 0; i < 4; ++i)
            b[i] = *reinterpret_cast<const bf16x8*>(Wbase + (size_t)i * 16 * K + kt);
#pragma unroll
        for (int mi = 0; mi < 4; ++mi)
#pragma unroll
            for (int ni = 0; ni < 4; ++ni)
                acc[mi][ni] = __builtin_amdgcn_mfma_f32_16x16x32_bf16(a[mi], b[ni], acc[mi][ni], 0, 0, 0);
    }

    int orow = (lane >> 4) * 4;
    int ocol = lane & 15;
#pragma unroll
    for (int mi = 0; mi < 4; ++mi)
#pragma unroll
        for (int ni = 0; ni < 4; ++ni)
#pragma unroll
            for (int j = 0; j < 4; ++j) {
                float v = fmaxf(acc[mi][ni][j], 0.0f);
                C[(size_t)(m0 + mi * 16 + orow + j) * ldc + (n0 + ni * 16 + ocol)] = (__bf16)v;
            }
}

// ---- final GEMM: out = embd @ W3^T, M=4096, N=64, K=256, fp32 out ---------
__global__ __launch_bounds__(256) void gemm_out(const __bf16* __restrict__ A,
                                                const __bf16* __restrict__ W,
                                                float* __restrict__ C) {
    const int K = 256;
    int wid  = threadIdx.x >> 6;
    int lane = threadIdx.x & 63;
    int m0 = blockIdx.x * 128 + wid * 32;
    int lr = lane & 15;
    int kg = lane >> 4;

    f32x4 acc[2][4] = {};
    const __bf16* Abase = A + (size_t)(m0 + lr) * K + kg * 8;
    const __bf16* Wbase = W + (size_t)lr * K + kg * 8;

    for (int kt = 0; kt < K; kt += 32) {
        bf16x8 a[2], b[4];
#pragma unroll
        for (int i = 0; i < 2; ++i)
            a[i] = *reinterpret_cast<const bf16x8*>(Abase + (size_t)i * 16 * K + kt);
#pragma unroll
        for (int i = 0; i < 4; ++i)
            b[i] = *reinterpret_cast<const bf16x8*>(Wbase + (size_t)i * 16 * K + kt);
#pragma unroll
        for (int mi = 0; mi < 2; ++mi)
#pragma unroll
            for (int ni = 0; ni < 4; ++ni)
                acc[mi][ni] = __builtin_amdgcn_mfma_f32_16x16x32_bf16(a[mi], b[ni], acc[mi][ni], 0, 0, 0);
    }

    int orow = (lane >> 4) * 4;
    int ocol = lane & 15;
#pragma unroll
    for (int mi = 0; mi < 2; ++mi)
#pragma unroll
        for (int ni = 0; ni < 4; ++ni)
#pragma unroll
            for (int j = 0; j < 4; ++j)
                C[(size_t)(m0 + mi * 16 + orow + j) * 64 + (ni * 16 + ocol)] = acc[mi][ni][j];
}

extern "C" void kernel_launch(void* const* d_in, const int* in_sizes, int n_in,
                              void* d_out, int out_size, void* d_ws, size_t ws_size,
                              hipStream_t stream) {
    const int*   T0  = (const int*)d_in[0];
    const int*   T1  = (const int*)d_in[1];
    const int*   T2  = (const int*)d_in[2];
    const float* emb = (const float*)d_in[3];
    const float* W1  = (const float*)d_in[4];
    const float* W2  = (const float*)d_in[5];
    const float* W3  = (const float*)d_in[6];
    float* out = (float*)d_out;

    char* ws = (char*)d_ws;
    __bf16*        Wzy  = (__bf16*)(ws);                 //   262144
    __bf16*        W2b  = (__bf16*)(ws + 262144);        //   262144
    __bf16*        W3b  = (__bf16*)(ws + 524288);        //    32768
    __bf16*        comb = (__bf16*)(ws + 557056);        //  4194304
    __bf16*        embd = (__bf16*)(ws + 4751360);       //  2097152
    __bf16*        Ztab = (__bf16*)(ws + 6848512);       // 51200000
    unsigned char* Y8   = (unsigned char*)(ws + 58048512); // 25600000 -> ends 83648512

    prep_wzy<<<dim3(64), dim3(256), 0, stream>>>(W1, Wzy);
    cvt_bf16_8<<<dim3(64), dim3(256), 0, stream>>>(W2, W2b, 131072 / 8);
    cvt_bf16_8<<<dim3(8), dim3(256), 0, stream>>>(W3, W3b, 16384 / 8);

    gemm_ZY<<<dim3(ZY_BLOCKS), dim3(512), 0, stream>>>(emb, Wzy, Ztab, Y8);

    agg_kernel<<<dim3(BATCH), dim3(256), 0, stream>>>(T0, T1, T2, Ztab, Y8, comb);

    gemm_relu_bf16<<<dim3(BATCH / 128, 2), dim3(256), 0, stream>>>(comb, W2b, embd, 512, 256);
    gemm_out<<<dim3(BATCH / 128), dim3(256), 0, stream>>>(embd, W3b, out);
}